// Round 7
// baseline (253.156 us; speedup 1.0000x reference)
//
#include <hip/hip_runtime.h>
#include <hip/hip_fp16.h>
#include <cstdint>

#define B_    2
#define T_    2048
#define H_    1024
#define DIN_  2048
#define NS_   16
#define M_    (B_*T_)     // 4096
#define NCHUNK 32
#define LCHUNK 64         // T_/NCHUNK

using bf16x8 = __attribute__((ext_vector_type(8))) short;
using f32x4  = __attribute__((ext_vector_type(4))) float;

__device__ __forceinline__ unsigned short f2bf(float f) {
    union { float f; uint32_t u; } x; x.f = f;
    uint32_t u = x.u;
    uint32_t r = (u + 0x7fffu + ((u >> 16) & 1u)) >> 16;
    return (unsigned short)r;
}
__device__ __forceinline__ float bf2f(unsigned short h) {
    union { uint32_t u; float f; } x; x.u = ((uint32_t)h) << 16;
    return x.f;
}
__device__ __forceinline__ float sigm(float v) { return 1.0f / (1.0f + expf(-v)); }
__device__ __forceinline__ float silu(float v) { return v / (1.0f + expf(-v)); }

__device__ __forceinline__ void gload_lds16(const void* g, void* l) {
    __builtin_amdgcn_global_load_lds(
        (__attribute__((address_space(1))) void*)(void*)g,
        (__attribute__((address_space(3))) void*)l, 16, 0, 0);
}

// ---------------- fused weight prep: transposes to bf16 [N][K] ----------------
// [0,4096) in_proj -> inT; [4096,8192) A_proj -> W2; [8192,10240) out_proj -> outT;
// [10240,10368) B/C_proj -> W2 rows 2048..2079; [10368,10380) zero W2 rows 2080..2175
__global__ __launch_bounds__(256)
void prep_weights(const float* __restrict__ in_proj, const float* __restrict__ A_proj,
                  const float* __restrict__ B_proj, const float* __restrict__ C_proj,
                  const float* __restrict__ out_proj,
                  unsigned short* __restrict__ inT, unsigned short* __restrict__ W2,
                  unsigned short* __restrict__ outT) {
    int bid = blockIdx.x;
    int tid = threadIdx.x;
    if (bid >= 10368) {        // zero pad rows 2080..2175 (96 rows, 12 blocks x 8 rows)
        int l = bid - 10368;
        uint4* p = (uint4*)&W2[(size_t)(2080 + l * 8) * 2048];
        uint4 z = make_uint4(0, 0, 0, 0);
#pragma unroll
        for (int i = 0; i < 8; ++i) p[tid * 8 + i] = z;
        return;
    }
    if (bid >= 10240) {        // B/C_proj: 16-wide transpose
        int l = bid - 10240;
        const float* src = (l < 64) ? B_proj : C_proj;
        int rowoff = (l < 64) ? 2048 : 2064;
        int k0 = (l & 63) * 32;
        int r = tid >> 4, c = tid & 15;     // r 0..15, c 0..15
#pragma unroll
        for (int rr = 0; rr < 32; rr += 16) {
            float v = src[(size_t)(k0 + r + rr) * 16 + c];
            W2[(size_t)(rowoff + c) * 2048 + (k0 + r + rr)] = f2bf(v);
        }
        return;
    }
    const float* src; unsigned short* dst; int K, N, l;
    if (bid < 4096)      { src = in_proj;  dst = inT;  K = 1024; N = 4096; l = bid; }
    else if (bid < 8192) { src = A_proj;   dst = W2;   K = 2048; N = 2048; l = bid - 4096; }
    else                 { src = out_proj; dst = outT; K = 2048; N = 1024; l = bid - 8192; }
    int ntiles = N >> 5;
    int n0 = (l % ntiles) * 32, k0 = (l / ntiles) * 32;
    __shared__ float tile[32][33];
    int tx = tid & 31, ty = tid >> 5;   // ty 0..7
#pragma unroll
    for (int i = 0; i < 32; i += 8)
        tile[ty + i][tx] = src[(size_t)(k0 + ty + i) * N + (n0 + tx)];
    __syncthreads();
    int sx = (tid & 15) * 2;   // k offset, even
    int sy = tid >> 4;         // n 0..15
#pragma unroll
    for (int i = 0; i < 32; i += 16) {
        int n = sy + i;
        float v0 = tile[sx][n], v1 = tile[sx + 1][n];
        size_t o = (size_t)(n0 + n) * K + (k0 + sx);
        *(ushort2*)&dst[o] = make_ushort2(f2bf(v0), f2bf(v1));
    }
}

// ---------------- RMSNorm -> single bf16 ----------------
__global__ __launch_bounds__(256)
void rmsnorm_bf(const float* __restrict__ x, const float* __restrict__ w,
                unsigned short* __restrict__ xh) {
    int row = blockIdx.x;            // 0..4095
    int tid = threadIdx.x;
    const float4* xr = (const float4*)(x + (size_t)row * H_);
    float4 v = xr[tid];
    float ss = v.x * v.x + v.y * v.y + v.z * v.z + v.w * v.w;
#pragma unroll
    for (int o = 32; o > 0; o >>= 1) ss += __shfl_down(ss, o, 64);
    __shared__ float red[4];
    int lane = tid & 63, wv = tid >> 6;
    if (lane == 0) red[wv] = ss;
    __syncthreads();
    float tot = red[0] + red[1] + red[2] + red[3];
    float rstd = rsqrtf(tot / (float)H_ + 1e-6f);
    const float4* wr = (const float4*)w;
    float4 w4 = wr[tid];
    size_t o = (size_t)row * H_ + tid * 4;
    *(ushort4*)&xh[o] = make_ushort4(f2bf(v.x * rstd * w4.x), f2bf(v.y * rstd * w4.y),
                                     f2bf(v.z * rstd * w4.z), f2bf(v.w * rstd * w4.w));
}

// ---------------- big-tile GEMM: C = A @ B^T, 256 x TN tile, BK=64, 8 waves ----------------
// 2 full-K-tile LDS buffers; depth-1 prefetch into opposite parity (race-free by
// construction: stage target is never the buffer being read; the single leading
// barrier is the handoff). vmcnt(0) is instant from iter 1 (loads issued 1 iter ago).
// Unit layout (16 rows x 64B, bank-group XOR swizzle) proven in r5: 0 conflicts.
// EPI 0: xz -> silu; col<2048: x_in bf16, else silu_z bf16
// EPI 1: col<2048: a_mod=sigm(acc+aux[col]) fp16; 2048..2063: Bin; 2064..2079: Cin; else skip
template <int EPI, int TN>
__global__ __launch_bounds__(512, 2)
void gemm_big(const unsigned short* __restrict__ Aa, const unsigned short* __restrict__ Bw,
              int K,
              unsigned short* __restrict__ oh, unsigned short* __restrict__ oz,
              const float* __restrict__ aux,
              __half* __restrict__ oha, float* __restrict__ obin, float* __restrict__ ocin) {
    constexpr int UA  = 32;            // A units: 16 chunks x 2 ksubs (256 rows)
    constexpr int UB  = (TN / 16) * 2; // B units
    constexpr int U   = UA + UB;
    constexpr int SPW = U / 8;         // stage loads per wave per K-tile (8 or 6)
    constexpr int WN  = TN / 64;       // n-frags per wave (4 or 2)
    __shared__ unsigned short sm[2][U * 512];
    const int tid  = threadIdx.x;
    const int lane = tid & 63;
    const int wid  = tid >> 6;
    const int wm   = wid >> 2;         // 0..1  (2M)
    const int wn   = wid & 3;          // 0..3  (4N)

    // XCD-chunked bijective block swizzle (grid %8 == 0)
    const int gx   = gridDim.x;
    const int nwg  = gx * gridDim.y;
    const int orig = blockIdx.y * gx + blockIdx.x;
    const int qq   = nwg >> 3;
    const int lid  = (orig & 7) * qq + (orig >> 3);
    const int bm   = (lid / gx) * 256;
    const int bn   = (lid % gx) * TN;

    // staging: unit = 16 rows x 32 k (1KB); lane -> row lane>>2, src granule swizzled
    const unsigned short* b0 = Aa + (size_t)bm * K;
    const unsigned short* b1 = Bw + (size_t)bn * K;
    const int srow  = lane >> 2;
    const int sgran = (lane & 3) ^ ((lane >> 3) & 3);
    const unsigned short* gp[SPW];
    int lofs[SPW];
#pragma unroll
    for (int j = 0; j < SPW; ++j) {
        int un = wid * SPW + j;
        int rel = (un < UA) ? un : (un - UA);
        const unsigned short* base = (un < UA) ? b0 : b1;
        int chunk = rel >> 1, ks = rel & 1;
        gp[j] = base + (size_t)(chunk * 16 + srow) * K + ks * 32 + sgran * 8;
        lofs[j] = un * 512;
    }

    const int nt = K >> 6;
    // prologue: stage K-tile 0 into buf 0
#pragma unroll
    for (int j = 0; j < SPW; ++j) gload_lds16(gp[j], &sm[0][lofs[j]]);

    // frag read offset (ushorts) within a unit: proven swizzle
    const int fro = (lane & 15) * 32 + (((lane >> 4) ^ ((lane >> 1) & 3)) * 8);

    f32x4 acc[8][WN] = {};
    for (int kt = 0; kt < nt; ++kt) {
        asm volatile("s_waitcnt vmcnt(0)" ::: "memory");   // K(kt) landed (instant for kt>=1)
        __builtin_amdgcn_s_barrier();                      // handoff: everyone done with buf[(kt+1)&1]
        __builtin_amdgcn_sched_barrier(0);
        if (kt + 1 < nt) {                                 // stage next K-tile, opposite parity
#pragma unroll
            for (int j = 0; j < SPW; ++j)
                gload_lds16(gp[j] + (kt + 1) * 64, &sm[(kt + 1) & 1][lofs[j]]);
        }
        const unsigned short* sb = sm[kt & 1];
#pragma unroll
        for (int ks = 0; ks < 2; ++ks) {
            bf16x8 af[8], bf8[WN];
#pragma unroll
            for (int mf = 0; mf < 8; ++mf)
                af[mf] = *(const bf16x8*)&sb[((wm * 8 + mf) * 2 + ks) * 512 + fro];
#pragma unroll
            for (int nf = 0; nf < WN; ++nf)
                bf8[nf] = *(const bf16x8*)&sb[(UA + (wn * WN + nf) * 2 + ks) * 512 + fro];
            __builtin_amdgcn_s_setprio(1);
#pragma unroll
            for (int mf = 0; mf < 8; ++mf)
#pragma unroll
                for (int nf = 0; nf < WN; ++nf)
                    acc[mf][nf] = __builtin_amdgcn_mfma_f32_16x16x32_bf16(af[mf], bf8[nf], acc[mf][nf], 0, 0, 0);
            __builtin_amdgcn_s_setprio(0);
        }
    }

    // epilogue: C/D layout col=lane&15, row=(lane>>4)*4+reg
#pragma unroll
    for (int mf = 0; mf < 8; ++mf)
#pragma unroll
        for (int nf = 0; nf < WN; ++nf) {
            int col  = bn + wn * (TN / 4) + nf * 16 + (lane & 15);
            int row0 = bm + wm * 128 + mf * 16 + ((lane >> 4) << 2);
#pragma unroll
            for (int r = 0; r < 4; ++r) {
                int row = row0 + r;
                float v = acc[mf][nf][r];
                if (EPI == 0) {
                    float s = silu(v);
                    if (col < DIN_) oh[(size_t)row * DIN_ + col] = f2bf(s);
                    else            oz[(size_t)row * DIN_ + (col - DIN_)] = f2bf(s);
                } else {
                    if (col < 2048)      oha[(size_t)row * DIN_ + col] = __float2half(sigm(v + aux[col]));
                    else if (col < 2064) obin[(size_t)row * 16 + (col - 2048)] = v;
                    else if (col < 2080) ocin[(size_t)row * 16 + (col - 2064)] = v;
                    // col >= 2080: pad, skip
                }
            }
        }
}

// ---------------- small GEMM (kept for G3): C = A @ B^T, TM x 128 tile ----------------
template <int EPI, int TM>
__global__ __launch_bounds__(256)
void gemm_bf(const unsigned short* __restrict__ Aa, const unsigned short* __restrict__ Bw,
             int K, float* __restrict__ out0, const float* __restrict__ aux) {
    constexpr int UA    = TM / 16;
    constexpr int UNITS = UA + 8;
    constexpr int SPW   = UNITS / 4;
    constexpr int WM    = (TM * 2) / (4 * 16);
    __shared__ unsigned short sm[3][UNITS * 512];
    const int tid  = threadIdx.x;
    const int lane = tid & 63;
    const int wid  = tid >> 6;
    const int wm   = wid >> 1, wn = wid & 1;

    const int gx   = gridDim.x;
    const int nwg  = gx * gridDim.y;
    const int orig = blockIdx.y * gx + blockIdx.x;
    const int qq   = nwg >> 3;
    const int lid  = (orig & 7) * qq + (orig >> 3);
    const int bm   = (lid / gx) * TM;
    const int bn   = (lid % gx) * 128;

    const unsigned short* b0 = Aa + (size_t)bm * K;
    const unsigned short* b1 = Bw + (size_t)bn * K;
    const int srow  = lane >> 2;
    const int sgran = (lane & 3) ^ ((lane >> 3) & 3);
    const unsigned short* gp[SPW];
    int lofs[SPW];
#pragma unroll
    for (int j = 0; j < SPW; ++j) {
        int u = wid * SPW + j;
        const unsigned short* base = (u < UA) ? b0 : b1;
        int chunk = (u < UA) ? u : (u - UA);
        gp[j] = base + (size_t)(chunk * 16 + srow) * K + sgran * 8;
        lofs[j] = u * 512;
    }

    const int nk = K >> 5;
#pragma unroll
    for (int j = 0; j < SPW; ++j) gload_lds16(gp[j], &sm[0][lofs[j]]);
#pragma unroll
    for (int j = 0; j < SPW; ++j) gload_lds16(gp[j] + 32, &sm[1][lofs[j]]);

    const int fro = (lane & 15) * 32 + (((lane >> 4) ^ ((lane >> 1) & 3)) * 8);

    f32x4 acc[WM][4] = {};
    int bsel = 0;
    for (int kt = 0; kt < nk; ++kt) {
        if (kt + 1 < nk) {
            if constexpr (SPW == 4) asm volatile("s_waitcnt vmcnt(4)" ::: "memory");
            else                    asm volatile("s_waitcnt vmcnt(3)" ::: "memory");
        } else {
            asm volatile("s_waitcnt vmcnt(0)" ::: "memory");
        }
        __builtin_amdgcn_s_barrier();
        __builtin_amdgcn_sched_barrier(0);
        if (kt + 2 < nk) {
            int nb = bsel + 2; if (nb >= 3) nb -= 3;
#pragma unroll
            for (int j = 0; j < SPW; ++j)
                gload_lds16(gp[j] + (kt + 2) * 32, &sm[nb][lofs[j]]);
        }
        const unsigned short* sb = sm[bsel];
        bf16x8 af[WM], bf8[4];
#pragma unroll
        for (int m = 0; m < WM; ++m)
            af[m] = *(const bf16x8*)&sb[(wm * WM + m) * 512 + fro];
#pragma unroll
        for (int n = 0; n < 4; ++n)
            bf8[n] = *(const bf16x8*)&sb[(UA + wn * 4 + n) * 512 + fro];
        __builtin_amdgcn_s_setprio(1);
#pragma unroll
        for (int m = 0; m < WM; ++m)
#pragma unroll
            for (int n = 0; n < 4; ++n)
                acc[m][n] = __builtin_amdgcn_mfma_f32_16x16x32_bf16(af[m], bf8[n], acc[m][n], 0, 0, 0);
        __builtin_amdgcn_s_setprio(0);
        bsel += 1; if (bsel == 3) bsel = 0;
    }

#pragma unroll
    for (int m = 0; m < WM; ++m)
#pragma unroll
        for (int n = 0; n < 4; ++n) {
            int col  = bn + wn * 64 + n * 16 + (lane & 15);
            int row0 = bm + wm * (WM * 16) + m * 16 + ((lane >> 4) << 2);
#pragma unroll
            for (int r = 0; r < 4; ++r) {
                int row = row0 + r;
                out0[(size_t)row * H_ + col] = acc[m][n][r] + aux[(size_t)row * H_ + col];
            }
        }
}

// ---------------- chunked parallel scan ----------------
__global__ __launch_bounds__(256)
void scan_phase1(const __half* __restrict__ amod, const unsigned short* __restrict__ xh,
                 const float* __restrict__ Bin, const float* __restrict__ Abase,
                 float* __restrict__ P, float* __restrict__ S) {
    int d = blockIdx.x * 256 + threadIdx.x;   // 0..2047
    int c = blockIdx.y;
    int b = blockIdx.z;
    float ab[16];
#pragma unroll
    for (int n = 0; n < 16; ++n) ab[n] = sigm(Abase[n]);
    float p[16], s[16];
#pragma unroll
    for (int n = 0; n < 16; ++n) { p[n] = 1.0f; s[n] = 0.0f; }
    int t0 = c * LCHUNK;
    for (int tt = 0; tt < LCHUNK; ++tt) {
        size_t mrow = (size_t)(b * T_ + t0 + tt);
        float a = __half2float(amod[mrow * DIN_ + d]);
        float x = bf2f(xh[mrow * DIN_ + d]);
        const float4* bt4 = (const float4*)(Bin + mrow * 16);
        float4 q0 = bt4[0], q1 = bt4[1], q2 = bt4[2], q3 = bt4[3];
        float bt[16];
        bt[0]=q0.x; bt[1]=q0.y; bt[2]=q0.z; bt[3]=q0.w;
        bt[4]=q1.x; bt[5]=q1.y; bt[6]=q1.z; bt[7]=q1.w;
        bt[8]=q2.x; bt[9]=q2.y; bt[10]=q2.z; bt[11]=q2.w;
        bt[12]=q3.x; bt[13]=q3.y; bt[14]=q3.z; bt[15]=q3.w;
#pragma unroll
        for (int n = 0; n < 16; ++n) {
            float dk = a * ab[n];
            p[n] *= dk;
            s[n] = fmaf(dk, s[n], bt[n] * x);
        }
    }
    size_t base = ((size_t)(b * NCHUNK + c) << 15) + (size_t)d * 16;
    float4* P4 = (float4*)(P + base);
    float4* S4 = (float4*)(S + base);
#pragma unroll
    for (int j = 0; j < 4; ++j) {
        P4[j] = make_float4(p[4*j], p[4*j+1], p[4*j+2], p[4*j+3]);
        S4[j] = make_float4(s[4*j], s[4*j+1], s[4*j+2], s[4*j+3]);
    }
}

__global__ __launch_bounds__(256)
void scan_phase2(const float* __restrict__ P, const float* __restrict__ S,
                 float* __restrict__ H0) {
    int idx = blockIdx.x * 256 + threadIdx.x;   // 0..65535
    int b = idx >> 15;
    int dn = idx & 32767;
    float g = 0.f;
    for (int c = 0; c < NCHUNK; ++c) {
        size_t base = ((size_t)(b * NCHUNK + c) << 15) + dn;
        H0[base] = g;
        g = fmaf(P[base], g, S[base]);
    }
}

__global__ __launch_bounds__(256)
void scan_phase3(const __half* __restrict__ amod, const unsigned short* __restrict__ xh,
                 const float* __restrict__ Bin, const float* __restrict__ Cin,
                 const float* __restrict__ Abase, const float* __restrict__ H0,
                 const float* __restrict__ Dp, const unsigned short* __restrict__ szh,
                 unsigned short* __restrict__ yh) {
    int d = blockIdx.x * 256 + threadIdx.x;
    int c = blockIdx.y;
    int b = blockIdx.z;
    float ab[16];
#pragma unroll
    for (int n = 0; n < 16; ++n) ab[n] = sigm(Abase[n]);
    float h[16];
    size_t hbase = ((size_t)(b * NCHUNK + c) << 15) + (size_t)d * 16;
    const float4* H4 = (const float4*)(H0 + hbase);
#pragma unroll
    for (int j = 0; j < 4; ++j) {
        float4 t4 = H4[j];
        h[j*4] = t4.x; h[j*4+1] = t4.y; h[j*4+2] = t4.z; h[j*4+3] = t4.w;
    }
    float Dd = Dp[d];
    int t0 = c * LCHUNK;
    for (int tt = 0; tt < LCHUNK; ++tt) {
        size_t mrow = (size_t)(b * T_ + t0 + tt);
        float a = __half2float(amod[mrow * DIN_ + d]);
        float x = bf2f(xh[mrow * DIN_ + d]);
        const float4* bt4 = (const float4*)(Bin + mrow * 16);
        const float4* ct4 = (const float4*)(Cin + mrow * 16);
        float4 q0 = bt4[0], q1 = bt4[1], q2 = bt4[2], q3 = bt4[3];
        float4 r0 = ct4[0], r1 = ct4[1], r2 = ct4[2], r3 = ct4[3];
        float bt[16], ct[16];
        bt[0]=q0.x; bt[1]=q0.y; bt[2]=q0.z; bt[3]=q0.w;
        bt[4]=q1.x; bt[5]=q1.y; bt[6]=q1.z; bt[7]=q1.w;
        bt[8]=q2.x; bt[9]=q2.y; bt[10]=q2.z; bt[11]=q2.w;
        bt[12]=q3.x; bt[13]=q3.y; bt[14]=q3.z; bt[15]=q3.w;
        ct[0]=r0.x; ct[1]=r0.y; ct[2]=r0.z; ct[3]=r0.w;
        ct[4]=r1.x; ct[5]=r1.y; ct[6]=r1.z; ct[7]=r1.w;
        ct[8]=r2.x; ct[9]=r2.y; ct[10]=r2.z; ct[11]=r2.w;
        ct[12]=r3.x; ct[13]=r3.y; ct[14]=r3.z; ct[15]=r3.w;
        float y = 0.f;
#pragma unroll
        for (int n = 0; n < 16; ++n) {
            float dk = a * ab[n];
            h[n] = fmaf(dk, h[n], bt[n] * x);
            y = fmaf(h[n], ct[n], y);
        }
        float val = (y + Dd * x) * bf2f(szh[mrow * DIN_ + d]);
        yh[mrow * DIN_ + d] = f2bf(val);
    }
}

// ---------------- launch ----------------
extern "C" void kernel_launch(void* const* d_in, const int* in_sizes, int n_in,
                              void* d_out, int out_size, void* d_ws, size_t ws_size,
                              hipStream_t stream) {
    const float* x          = (const float*)d_in[0];
    const float* norm_w     = (const float*)d_in[1];
    const float* in_proj_w  = (const float*)d_in[2];
    const float* A_proj_w   = (const float*)d_in[3];
    const float* A_proj_b   = (const float*)d_in[4];
    const float* A_base     = (const float*)d_in[5];
    const float* B_proj_w   = (const float*)d_in[6];
    const float* C_proj_w   = (const float*)d_in[7];
    const float* Dp         = (const float*)d_in[8];
    const float* out_proj_w = (const float*)d_in[9];
    float* out = (float*)d_out;

    char* ws = (char*)d_ws;
    size_t off = 0;
    auto alloc = [&](size_t bytes) -> char* {
        char* p = ws + off;
        off += (bytes + 255) & ~(size_t)255;
        return p;
    };
    unsigned short* inT  = (unsigned short*)alloc((size_t)4096 * 1024 * 2);
    unsigned short* W2   = (unsigned short*)alloc((size_t)2176 * 2048 * 2);  // A|B|C|zero-pad
    unsigned short* outT = (unsigned short*)alloc((size_t)1024 * 2048 * 2);
    unsigned short* xnh  = (unsigned short*)alloc((size_t)M_ * H_ * 2);
    unsigned short* xinh = (unsigned short*)alloc((size_t)M_ * DIN_ * 2);
    unsigned short* szh  = (unsigned short*)alloc((size_t)M_ * DIN_ * 2);
    __half* amod  = (__half*)alloc((size_t)M_ * DIN_ * 2);
    float* Bin    = (float*)alloc((size_t)M_ * 16 * 4);
    float* Cin    = (float*)alloc((size_t)M_ * 16 * 4);
    float* Pw     = (float*)alloc((size_t)B_ * NCHUNK * DIN_ * NS_ * 4);
    float* Sw     = (float*)alloc((size_t)B_ * NCHUNK * DIN_ * NS_ * 4);
    float* H0w    = (float*)alloc((size_t)B_ * NCHUNK * DIN_ * NS_ * 4);
    unsigned short* yh = (unsigned short*)alloc((size_t)M_ * DIN_ * 2);
    (void)ws_size;

    // fused weight prep (all transposes + pad-zeroing in one launch)
    prep_weights<<<10380, 256, 0, stream>>>(in_proj_w, A_proj_w, B_proj_w, C_proj_w,
                                            out_proj_w, inT, W2, outT);

    rmsnorm_bf<<<M_, 256, 0, stream>>>(x, norm_w, xnh);

    // xz = xn @ in_proj  (M=4096, N=4096, K=1024): 256x256 tiles -> 256 blocks, nt=16
    gemm_big<0, 256><<<dim3(4096 / 256, M_ / 256), 512, 0, stream>>>(
        xnh, inT, 1024, xinh, szh, nullptr, nullptr, nullptr, nullptr);

    // [a_mod | B_in | C_in] = x_in @ [A|B|C]  (N=2176 in 17 x 128-col tiles, K=2048) -> 272 blocks
    gemm_big<1, 128><<<dim3(2176 / 128, M_ / 256), 512, 0, stream>>>(
        xinh, W2, 2048, nullptr, nullptr, A_proj_b, amod, Bin, Cin);

    // chunked scan
    scan_phase1<<<dim3(DIN_ / 256, NCHUNK, B_), 256, 0, stream>>>(amod, xinh, Bin, A_base, Pw, Sw);
    scan_phase2<<<(B_ * DIN_ * NS_) / 256, 256, 0, stream>>>(Pw, Sw, H0w);
    scan_phase3<<<dim3(DIN_ / 256, NCHUNK, B_), 256, 0, stream>>>(
        amod, xinh, Bin, Cin, A_base, H0w, Dp, szh, yh);

    // out = residual + y @ out_proj  (N=1024, K=2048), 64x128 tiles -> 512 blocks
    gemm_bf<2, 64><<<dim3(1024 / 128, M_ / 64), 256, 0, stream>>>(
        yh, outT, 2048, out, x);
}